// Round 6
// baseline (681.911 us; speedup 1.0000x reference)
//
#include <hip/hip_runtime.h>
#include <math.h>

#define B_ 16
#define L_ 4096
#define H_ 8
#define E_ 64
#define C_ 512     // H*E
#define K_ 24
#define NT 256
#define RPAD 257   // padded row stride (float2 units) for the 16x256 LDS matrix
#define WSZ 4112   // 16*RPAD, per-channel FFT work size (float2)

__device__ __forceinline__ float2 cmul(float2 a, float2 b) {
    return make_float2(a.x * b.x - a.y * b.y, a.x * b.y + a.y * b.x);
}
__device__ __forceinline__ float2 cadd(float2 a, float2 b) { return make_float2(a.x + b.x, a.y + b.y); }
__device__ __forceinline__ float2 csub(float2 a, float2 b) { return make_float2(a.x - b.x, a.y - b.y); }

// barrier that orders LDS only: does NOT drain vmcnt, so register prefetch
// loads stay in flight across it (no cross-thread global deps at these points)
__device__ __forceinline__ void bar_lds() {
    asm volatile("s_waitcnt lgkmcnt(0)" ::: "memory");
    __builtin_amdgcn_s_barrier();
}

// 16-point DIF FFT, natural-order input; output: X[k] = a[br4[k]]
__device__ __forceinline__ void fft16(float2 a[16]) {
    const float r2 = 0.70710678118654752f;
    const float c1 = 0.92387953251128676f;  // cos(pi/8)
    const float s1 = 0.38268343236508977f;  // sin(pi/8)
    const float2 W16[8] = {
        make_float2(1.f, 0.f),  make_float2(c1, -s1),  make_float2(r2, -r2),  make_float2(s1, -c1),
        make_float2(0.f, -1.f), make_float2(-s1, -c1), make_float2(-r2, -r2), make_float2(-c1, -s1)};
    #pragma unroll
    for (int j = 0; j < 8; ++j) {
        float2 u = a[j], v = a[j + 8];
        a[j]     = cadd(u, v);
        a[j + 8] = cmul(csub(u, v), W16[j]);
    }
    #pragma unroll
    for (int b = 0; b < 16; b += 8)
        #pragma unroll
        for (int j = 0; j < 4; ++j) {
            float2 u = a[b + j], v = a[b + j + 4];
            a[b + j]     = cadd(u, v);
            a[b + j + 4] = cmul(csub(u, v), W16[2 * j]);
        }
    #pragma unroll
    for (int b = 0; b < 16; b += 4)
        #pragma unroll
        for (int j = 0; j < 2; ++j) {
            float2 u = a[b + j], v = a[b + j + 2];
            a[b + j]     = cadd(u, v);
            a[b + j + 2] = cmul(csub(u, v), W16[4 * j]);
        }
    #pragma unroll
    for (int b = 0; b < 16; b += 2) {
        float2 u = a[b], v = a[b + 1];
        a[b]     = cadd(u, v);
        a[b + 1] = csub(u, v);
    }
}

// ---------------- zero scratch ----------------
__global__ __launch_bounds__(256) void k_zero(float* __restrict__ p, int n) {
    int i = blockIdx.x * 256 + threadIdx.x;
    if (i < n) p[i] = 0.f;
}

// ---------------- fully fused forward FFT + cross-spectrum ----------------
// Block: 1024 threads (4 groups x 256), one batch x 8 channels (2 rounds of 4).
// amdgpu_waves_per_eu(4,4): pins the regalloc occupancy target to EXACTLY
// 4 waves/EU (the LDS-imposed ceiling anyway: 133KB -> 1 block/CU = 16 waves)
// -> 512/4 = 128-VGPR budget. Rounds 4+5 post-mortem: default budget 64 and
// __launch_bounds__(1024,4) (a MINIMUM, regalloc still targeted 8 waves/EU)
// both left VGPR=64 -> ~50 regs spilled -> 750MB scratch W + 400MB scratch R.
// Peak live set ~110 by construction: a[16] dead during accumulate (qr/kr
// live), qr/kr dead during phases A-C (a[16] live).
// LDS: union(stg 128KB, work 4x32.9KB=131.6KB) + tw256 -> 133.6KB, 1 block/CU.
__global__ __launch_bounds__(1024)
__attribute__((amdgpu_waves_per_eu(4, 4)))
void k_fft_full(const float* __restrict__ q,
                const float* __restrict__ k,
                float* __restrict__ cross) {
    __shared__ float2 w4[4 * WSZ];    // 131,584 B union buffer
    __shared__ float2 tw256[256];     // tw256[r1*16+m2] = W256^{m2*r1}
    const int br4[16] = {0, 8, 4, 12, 2, 10, 6, 14, 1, 9, 5, 13, 3, 11, 7, 15};
    const int tid = threadIdx.x;
    const int t   = tid & 255;        // lane within group
    const int grp = tid >> 8;         // channel group 0..3

    // XCD-aware bijective decode: 1024 blocks, xcd = id&7 owns 2 whole batches
    int id = blockIdx.x;
    int wk = ((id & 7) << 7) | (id >> 3);
    int b  = wk >> 6;                 // 0..15
    int g  = wk & 63;                 // 8-channel group within batch

    if (tid < 256) {
        int r1 = tid >> 4, m2 = tid & 15;
        float sn, cs;
        sincospif((float)(r1 * m2) / 128.0f, &sn, &cs);
        tw256[tid] = make_float2(cs, -sn);
    }

    const int rowB = t >> 4, m2B = t & 15;
    const int k1C = t & 15, r1C = t >> 4;
    const int sw3 = (tid >> 3) & 3;   // swizzle term; == ((t>>3)&3) and ((tau>>3)&3)
    const int chx = grp ^ sw3;

    float accx[16], accy[16];
    #pragma unroll
    for (int r = 0; r < 16; ++r) { accx[r] = 0.f; accy[r] = 0.f; }

    // phase-A twiddle base W4096^t (hoisted; reused both rounds)
    float snA, csA;
    sincospif((float)t / 2048.0f, &snA, &csA);
    const float2 w1 = make_float2(csA, -snA);

    // ---- issue round-0 global loads ----
    const size_t rowbase = (size_t)b * L_ * C_;
    float4 qr[4], kr[4];
    {
        int cb = g << 2;
        #pragma unroll
        for (int it = 0; it < 4; ++it) {
            int tau = (it << 10) + tid;
            qr[it] = *(const float4*)(q + rowbase + (size_t)tau * C_ + cb);
            kr[it] = *(const float4*)(k + rowbase + (size_t)tau * C_ + cb);
        }
    }

    float2* wg = w4 + grp * WSZ;

    for (int rnd = 0; rnd < 2; ++rnd) {
        // ---- stage: interleave z = q + i*k, swizzled 4-ch rows ----
        #pragma unroll
        for (int it = 0; it < 4; ++it) {
            int tau = (it << 10) + tid;
            float2* row = w4 + (tau << 2);
            row[0 ^ sw3] = make_float2(qr[it].x, kr[it].x);
            row[1 ^ sw3] = make_float2(qr[it].y, kr[it].y);
            row[2 ^ sw3] = make_float2(qr[it].z, kr[it].z);
            row[3 ^ sw3] = make_float2(qr[it].w, kr[it].w);
        }
        __syncthreads();
        // ---- phase-A gather to registers (all groups read the whole stg) ----
        float2 a[16];
        #pragma unroll
        for (int n1 = 0; n1 < 16; ++n1)
            a[n1] = w4[(((n1 << 8) + t) << 2) + chx];
        bar_lds();   // every gather retired before phase-A writes overwrite stg
        // ---- phase A ----
        fft16(a);
        {
            float2 tw = w1;
            wg[t] = a[0];                       // k1 = 0
            #pragma unroll
            for (int k1 = 1; k1 < 16; ++k1) {
                wg[k1 * RPAD + t] = cmul(a[br4[k1]], tw);
                tw = cmul(tw, w1);
            }
        }
        __syncthreads();
        // ---- phase B (in-place, cells thread-exclusive) ----
        #pragma unroll
        for (int m1 = 0; m1 < 16; ++m1) a[m1] = wg[rowB * RPAD + (m1 << 4) + m2B];
        fft16(a);
        #pragma unroll
        for (int r1 = 0; r1 < 16; ++r1)
            wg[rowB * RPAD + (r1 << 4) + m2B] = cmul(a[br4[r1]], tw256[(r1 << 4) + m2B]);
        __syncthreads();
        // ---- phase C ----
        #pragma unroll
        for (int m2 = 0; m2 < 16; ++m2) a[m2] = wg[k1C * RPAD + (r1C << 4) + m2];
        fft16(a);
        __syncthreads();
        #pragma unroll
        for (int r2 = 0; r2 < 16; ++r2)
            wg[(r2 << 8) + (r1C << 4) + k1C] = a[br4[r2]];   // natural order, flat
        // ---- issue round-1 loads; they hide under the accumulate phase ----
        if (rnd == 0) {
            int cb = (g << 2) + 256;
            #pragma unroll
            for (int it = 0; it < 4; ++it) {
                int tau = (it << 10) + tid;
                qr[it] = *(const float4*)(q + rowbase + (size_t)tau * C_ + cb);
                kr[it] = *(const float4*)(k + rowbase + (size_t)tau * C_ + cb);
            }
        }
        bar_lds();   // LDS-ordering only; loads stay in flight
        // ---- unpack Z=Q+iK, accumulate Q*conj(K) ----
        #pragma unroll
        for (int r = 0; r < 16; ++r) {
            int p  = t + (r << 8);
            int pp = (L_ - p) & (L_ - 1);
            float2 A  = wg[p];
            float2 Bv = wg[pp];
            float Qr = 0.5f * (A.x + Bv.x);
            float Qi = 0.5f * (A.y - Bv.y);
            float Kr = 0.5f * (A.y + Bv.y);
            float Ki = 0.5f * (A.x - Bv.x);
            accx[r] += Qr * Kr - Qi * Ki;
            accy[r] += Qr * Ki + Qi * Kr;
        }
        bar_lds();   // accum reads done before next stage / reduction overwrites
    }

    // ---- cross-group reduction in LDS, then one atomic pass per block ----
    #pragma unroll
    for (int r = 0; r < 16; ++r)
        wg[t * 16 + (r ^ (t & 15))] = make_float2(accx[r], accy[r]);
    __syncthreads();
    float* crb = cross + (size_t)b * L_ * 2;
    #pragma unroll
    for (int rr = 0; rr < 4; ++rr) {
        int p  = tid + (rr << 10);
        int tl = p & 255, rv = p >> 8;
        float sx = 0.f, sy = 0.f;
        #pragma unroll
        for (int gg = 0; gg < 4; ++gg) {
            float2 vv = w4[gg * WSZ + tl * 16 + (rv ^ (tl & 15))];
            sx += vv.x; sy += vv.y;
        }
        atomicAdd(&crb[p * 2 + 0], sx);
        atomicAdd(&crb[p * 2 + 1], sy);
    }
}

// ---------------- inverse FFT via conj-forward 3-phase radix-16 ----------------
__global__ __launch_bounds__(256) void k_ifft(const float* __restrict__ cross,
                                              float* __restrict__ mv) {
    __shared__ float2 s[16 * RPAD];
    __shared__ float2 tw256[256];
    const int br4[16] = {0, 8, 4, 12, 2, 10, 6, 14, 1, 9, 5, 13, 3, 11, 7, 15};
    int t = threadIdx.x;
    int b = blockIdx.x;
    {
        int r1 = t >> 4, m2 = t & 15;
        float sn, cs;
        sincospif((float)(r1 * m2) / 128.0f, &sn, &cs);
        tw256[t] = make_float2(cs, -sn);
    }
    const float2* cr = (const float2*)cross + (size_t)b * L_;
    float2 a[16];
    #pragma unroll
    for (int n1 = 0; n1 < 16; ++n1) {
        float2 v = cr[(n1 << 8) + t];
        a[n1] = make_float2(v.x, -v.y);          // conj
    }
    // ---- phase A ----
    fft16(a);
    {
        float sn, cs;
        sincospif((float)t / 2048.0f, &sn, &cs);
        const float2 w1 = make_float2(cs, -sn);
        float2 tw = w1;
        s[t] = a[0];
        #pragma unroll
        for (int k1 = 1; k1 < 16; ++k1) {
            s[k1 * RPAD + t] = cmul(a[br4[k1]], tw);
            tw = cmul(tw, w1);
        }
    }
    __syncthreads();
    // ---- phase B ----
    const int rowB = t >> 4, m2B = t & 15;
    #pragma unroll
    for (int m1 = 0; m1 < 16; ++m1) a[m1] = s[rowB * RPAD + (m1 << 4) + m2B];
    fft16(a);
    #pragma unroll
    for (int r1 = 0; r1 < 16; ++r1)
        s[rowB * RPAD + (r1 << 4) + m2B] = cmul(a[br4[r1]], tw256[(r1 << 4) + m2B]);
    __syncthreads();
    // ---- phase C: write mv directly (k = r2*256 + t, coalesced) ----
    const int k1C = t & 15, r1C = t >> 4;
    #pragma unroll
    for (int m2 = 0; m2 < 16; ++m2) a[m2] = s[k1C * RPAD + (r1C << 4) + m2];
    fft16(a);
    const float scale = 1.0f / ((float)L_ * (float)C_);
    #pragma unroll
    for (int r2 = 0; r2 < 16; ++r2)
        mv[(size_t)b * L_ + (r2 << 8) + t] = a[br4[r2]].x * scale;
}

// ---------------- top-24 + per-batch softmax (register-resident, wave-shuffle) ----------------
__global__ __launch_bounds__(256) void k_topk(const float* __restrict__ mv,
                                              int* __restrict__ idx,
                                              float* __restrict__ wts) {
    __shared__ float wv[4];
    __shared__ int   wi[4];
    __shared__ int   idxL[K_];
    int tid = threadIdx.x;
    float vloc[16];
    #pragma unroll
    for (int r = 0; r < 16; ++r) {
        int tt = tid + (r << 8);
        float ssum = 0.f;
        for (int b = 0; b < B_; ++b) ssum += mv[(size_t)b * L_ + tt];
        vloc[r] = ssum;
    }
    int lane = tid & 63, w = tid >> 6;
    for (int i = 0; i < K_; ++i) {
        float best = -INFINITY; int bi = 1 << 30;
        #pragma unroll
        for (int r = 0; r < 16; ++r) {
            float v = vloc[r]; int ii = tid + (r << 8);
            if (v > best || (v == best && ii < bi)) { best = v; bi = ii; }
        }
        #pragma unroll
        for (int off = 32; off > 0; off >>= 1) {
            float ov = __shfl_down(best, off);
            int   oi = __shfl_down(bi, off);
            if (ov > best || (ov == best && oi < bi)) { best = ov; bi = oi; }
        }
        if (lane == 0) { wv[w] = best; wi[w] = bi; }
        __syncthreads();
        if (tid == 0) {
            float bb = wv[0]; int bj = wi[0];
            for (int j = 1; j < 4; ++j)
                if (wv[j] > bb || (wv[j] == bb && wi[j] < bj)) { bb = wv[j]; bj = wi[j]; }
            idxL[i] = bj; idx[i] = bj;
        }
        __syncthreads();
        int win = idxL[i];
        #pragma unroll
        for (int r = 0; r < 16; ++r)
            if (win == tid + (r << 8)) vloc[r] = -INFINITY;
    }
    if (tid < B_) {
        int b = tid;
        float ww[K_]; float wm = -INFINITY;
        for (int i = 0; i < K_; ++i) { ww[i] = mv[(size_t)b * L_ + idxL[i]]; wm = fmaxf(wm, ww[i]); }
        float ssum = 0.f;
        for (int i = 0; i < K_; ++i) { ww[i] = expf(ww[i] - wm); ssum += ww[i]; }
        float inv = 1.f / ssum;
        for (int i = 0; i < K_; ++i) wts[b * K_ + i] = ww[i] * inv;
    }
}

// ---------------- 24-tap circulant gather-sum, LDS tau-ring version ----------------
__global__ __launch_bounds__(256) void k_agg(const float* __restrict__ vals,
                                             const int* __restrict__ idx,
                                             const float* __restrict__ wts,
                                             float* __restrict__ out) {
    __shared__ float4 sv[L_];      // 64 KB ring: 2 blocks/CU
    __shared__ int   di[K_];
    __shared__ float dw[K_];
    const int tid = threadIdx.x;
    // XCD-aware bijective decode: 2048 blocks; xcd = id&7 owns work [xcd*256, xcd*256+256)
    int id = blockIdx.x;
    int wk = ((id & 7) << 8) | (id >> 3);
    int b  = wk >> 7;              // 0..15 (2 batches per XCD)
    int c0 = (wk & 127) << 2;      // channel-quad start

    if (tid < K_) { di[tid] = idx[tid]; dw[tid] = wts[b * K_ + tid]; }

    // ---- stage: 16 iters x 256 lanes x 16B, LDS dest linear (wave-uniform base + lane*16)
    const float* gbase = vals + (size_t)b * L_ * C_ + c0;
    #pragma unroll
    for (int it = 0; it < 16; ++it) {
        int tau = (it << 8) + tid;
        const float* g = gbase + (size_t)tau * C_;
        float4* l = &sv[(it << 8) + ((tid >> 6) << 6)];   // wave-uniform within each wave
        __builtin_amdgcn_global_load_lds(
            (const __attribute__((address_space(1))) uint32_t*)g,
            (__attribute__((address_space(3))) uint32_t*)l,
            16, 0, 0);
    }
    __syncthreads();   // drains vmcnt before barrier

    // taps/weights to registers (fully-unrolled static indexing)
    int   dir[K_]; float dwr[K_];
    #pragma unroll
    for (int i = 0; i < K_; ++i) { dir[i] = di[i]; dwr[i] = dw[i]; }

    float* obase = out + (size_t)b * L_ * C_ + c0;
    for (int r = 0; r < 16; ++r) {
        int tau = (r << 8) + tid;
        float4 acc = make_float4(0.f, 0.f, 0.f, 0.f);
        #pragma unroll
        for (int i = 0; i < K_; ++i) {
            float4 x = sv[(tau + dir[i]) & (L_ - 1)];
            float w = dwr[i];
            acc.x = fmaf(w, x.x, acc.x);
            acc.y = fmaf(w, x.y, acc.y);
            acc.z = fmaf(w, x.z, acc.z);
            acc.w = fmaf(w, x.w, acc.w);
        }
        *(float4*)(obase + (size_t)tau * C_) = acc;
    }
}

extern "C" void kernel_launch(void* const* d_in, const int* in_sizes, int n_in,
                              void* d_out, int out_size, void* d_ws, size_t ws_size,
                              hipStream_t stream) {
    const float* q = (const float*)d_in[0];
    const float* k = (const float*)d_in[1];
    const float* v = (const float*)d_in[2];
    float* out = (float*)d_out;
    char* ws = (char*)d_ws;

    // ws layout: [cross 512KB | mv 256KB | idx | wts]  (no z: fully fused FFT)
    float* cross = (float*)ws;
    float* mv    = (float*)(ws + (1 << 20));
    int*   idx   = (int*)(ws + (1 << 20) + (1 << 18));
    float* wts   = (float*)(ws + (1 << 20) + (1 << 18) + 4096);

    k_zero<<<(B_ * L_ * 2 + 255) / 256, 256, 0, stream>>>(cross, B_ * L_ * 2);
    k_fft_full<<<B_ * (C_ / 8), 1024, 0, stream>>>(q, k, cross);
    k_ifft<<<B_, 256, 0, stream>>>(cross, mv);
    k_topk<<<1, 256, 0, stream>>>(mv, idx, wts);
    k_agg<<<B_ * (C_ / 4), 256, 0, stream>>>(v, idx, wts, out);
}

// Round 7
// 395.528 us; speedup vs baseline: 1.7241x; 1.7241x over previous
//
#include <hip/hip_runtime.h>
#include <math.h>

#define B_ 16
#define L_ 4096
#define H_ 8
#define E_ 64
#define C_ 512     // H*E
#define K_ 24
#define NT 256
#define RPAD 257   // padded row stride (float2 units) for the 16x256 LDS matrix
#define WSZ 4112   // 16*RPAD, per-channel FFT work size (float2)

__device__ __forceinline__ float2 cmul(float2 a, float2 b) {
    return make_float2(a.x * b.x - a.y * b.y, a.x * b.y + a.y * b.x);
}
__device__ __forceinline__ float2 cadd(float2 a, float2 b) { return make_float2(a.x + b.x, a.y + b.y); }
__device__ __forceinline__ float2 csub(float2 a, float2 b) { return make_float2(a.x - b.x, a.y - b.y); }

// barrier that orders LDS only: does NOT drain vmcnt
__device__ __forceinline__ void bar_lds() {
    asm volatile("s_waitcnt lgkmcnt(0)" ::: "memory");
    __builtin_amdgcn_s_barrier();
}

// 16-point DIF FFT, natural-order input; output: X[k] = a[br4[k]]
__device__ __forceinline__ void fft16(float2 a[16]) {
    const float r2 = 0.70710678118654752f;
    const float c1 = 0.92387953251128676f;  // cos(pi/8)
    const float s1 = 0.38268343236508977f;  // sin(pi/8)
    const float2 W16[8] = {
        make_float2(1.f, 0.f),  make_float2(c1, -s1),  make_float2(r2, -r2),  make_float2(s1, -c1),
        make_float2(0.f, -1.f), make_float2(-s1, -c1), make_float2(-r2, -r2), make_float2(-c1, -s1)};
    #pragma unroll
    for (int j = 0; j < 8; ++j) {
        float2 u = a[j], v = a[j + 8];
        a[j]     = cadd(u, v);
        a[j + 8] = cmul(csub(u, v), W16[j]);
    }
    #pragma unroll
    for (int b = 0; b < 16; b += 8)
        #pragma unroll
        for (int j = 0; j < 4; ++j) {
            float2 u = a[b + j], v = a[b + j + 4];
            a[b + j]     = cadd(u, v);
            a[b + j + 4] = cmul(csub(u, v), W16[2 * j]);
        }
    #pragma unroll
    for (int b = 0; b < 16; b += 4)
        #pragma unroll
        for (int j = 0; j < 2; ++j) {
            float2 u = a[b + j], v = a[b + j + 2];
            a[b + j]     = cadd(u, v);
            a[b + j + 2] = cmul(csub(u, v), W16[4 * j]);
        }
    #pragma unroll
    for (int b = 0; b < 16; b += 2) {
        float2 u = a[b], v = a[b + 1];
        a[b]     = cadd(u, v);
        a[b + 1] = csub(u, v);
    }
}

// ---------------- zero scratch ----------------
__global__ __launch_bounds__(256) void k_zero(float* __restrict__ p, int n) {
    int i = blockIdx.x * 256 + threadIdx.x;
    if (i < n) p[i] = 0.f;
}

// ---------------- fully fused forward FFT + cross-spectrum (single round) ----------------
// Block: 1024 threads (4 groups x 256), one batch x 4 channels, ONE round.
// Rounds 4-6 post-mortem: the compiler pins 1024-thread kernels to a 64-VGPR
// budget (launch_bounds min-waves and amdgpu_waves_per_eu both ignored), and
// the 2-round structure made {acc, a[16], qr/kr} pairwise co-live (~110 regs)
// -> ~50 spilled -> 1.15 GB scratch traffic. Single-round fixes liveness BY
// CONSTRUCTION: qr/kr (32) die at staging, a[16] (32) dies before accumulate,
// acc (32) is born after. Peak live ~55 < 64 -> no scratch.
// Staging: 16B/lane scattered by 2KB; the 8 co-XCD sibling blocks covering
// each 128B line are consecutive wk on the same XCD -> L2 dedup (verified:
// rounds 4-6 FETCH input component ~= 256MB).
// LDS: union(stg 128KB, work 4x32.9KB=131.6KB) + tw256 -> 133.6KB, 1 block/CU.
__global__ __launch_bounds__(1024) void k_fft_full(const float* __restrict__ q,
                                                   const float* __restrict__ k,
                                                   float* __restrict__ cross) {
    __shared__ float2 w4[4 * WSZ];    // 131,584 B union buffer
    __shared__ float2 tw256[256];     // tw256[r1*16+m2] = W256^{m2*r1}
    const int br4[16] = {0, 8, 4, 12, 2, 10, 6, 14, 1, 9, 5, 13, 3, 11, 7, 15};
    const int tid = threadIdx.x;
    const int t   = tid & 255;        // lane within group
    const int grp = tid >> 8;         // channel group 0..3

    // XCD-aware bijective decode: 2048 blocks; xcd = id&7 owns 2 whole batches
    int id = blockIdx.x;
    int wk = ((id & 7) << 8) | (id >> 3);
    int b  = wk >> 7;                 // 0..15
    int g  = wk & 127;                // 4-channel group within batch
    int c0 = g << 2;

    if (tid < 256) {
        int r1 = tid >> 4, m2 = tid & 15;
        float sn, cs;
        sincospif((float)(r1 * m2) / 128.0f, &sn, &cs);
        tw256[tid] = make_float2(cs, -sn);
    }

    const int rowB = t >> 4, m2B = t & 15;
    const int k1C = t & 15, r1C = t >> 4;
    const int sw3 = (tid >> 3) & 3;   // swizzle term; == ((t>>3)&3) and ((tau>>3)&3)
    const int chx = grp ^ sw3;

    // ---- issue the block's global loads (4 ch x 4096 tau, 16B q + 16B k per lane-iter)
    const size_t rowbase = (size_t)b * L_ * C_;
    float4 qr[4], kr[4];
    #pragma unroll
    for (int it = 0; it < 4; ++it) {
        int tau = (it << 10) + tid;
        qr[it] = *(const float4*)(q + rowbase + (size_t)tau * C_ + c0);
        kr[it] = *(const float4*)(k + rowbase + (size_t)tau * C_ + c0);
    }

    float2* wg = w4 + grp * WSZ;

    // ---- stage: interleave z = q + i*k, swizzled 4-ch rows (qr/kr die here) ----
    #pragma unroll
    for (int it = 0; it < 4; ++it) {
        int tau = (it << 10) + tid;
        float2* row = w4 + (tau << 2);
        row[0 ^ sw3] = make_float2(qr[it].x, kr[it].x);
        row[1 ^ sw3] = make_float2(qr[it].y, kr[it].y);
        row[2 ^ sw3] = make_float2(qr[it].z, kr[it].z);
        row[3 ^ sw3] = make_float2(qr[it].w, kr[it].w);
    }
    __syncthreads();

    // ---- phase-A gather to registers ----
    float2 a[16];
    #pragma unroll
    for (int n1 = 0; n1 < 16; ++n1)
        a[n1] = w4[(((n1 << 8) + t) << 2) + chx];
    bar_lds();   // every gather retired before phase-A writes overwrite stg

    // ---- phase A ----
    fft16(a);
    {
        float snA, csA;
        sincospif((float)t / 2048.0f, &snA, &csA);
        const float2 w1 = make_float2(csA, -snA);
        float2 tw = w1;
        wg[t] = a[0];                       // k1 = 0
        #pragma unroll
        for (int k1 = 1; k1 < 16; ++k1) {
            wg[k1 * RPAD + t] = cmul(a[br4[k1]], tw);
            tw = cmul(tw, w1);
        }
    }
    __syncthreads();
    // ---- phase B (in-place, cells thread-exclusive) ----
    #pragma unroll
    for (int m1 = 0; m1 < 16; ++m1) a[m1] = wg[rowB * RPAD + (m1 << 4) + m2B];
    fft16(a);
    #pragma unroll
    for (int r1 = 0; r1 < 16; ++r1)
        wg[rowB * RPAD + (r1 << 4) + m2B] = cmul(a[br4[r1]], tw256[(r1 << 4) + m2B]);
    __syncthreads();
    // ---- phase C ----
    #pragma unroll
    for (int m2 = 0; m2 < 16; ++m2) a[m2] = wg[k1C * RPAD + (r1C << 4) + m2];
    fft16(a);
    __syncthreads();
    #pragma unroll
    for (int r2 = 0; r2 < 16; ++r2)
        wg[(r2 << 8) + (r1C << 4) + k1C] = a[br4[r2]];   // natural order, flat
    bar_lds();

    // ---- unpack Z=Q+iK, accumulate Q*conj(K) (a[] dead; acc born here) ----
    float accx[16], accy[16];
    #pragma unroll
    for (int r = 0; r < 16; ++r) {
        int p  = t + (r << 8);
        int pp = (L_ - p) & (L_ - 1);
        float2 A  = wg[p];
        float2 Bv = wg[pp];
        float Qr = 0.5f * (A.x + Bv.x);
        float Qi = 0.5f * (A.y - Bv.y);
        float Kr = 0.5f * (A.y + Bv.y);
        float Ki = 0.5f * (A.x - Bv.x);
        accx[r] = Qr * Kr - Qi * Ki;
        accy[r] = Qr * Ki + Qi * Kr;
    }
    bar_lds();   // all accum reads done before transpose-store overwrites wg

    // ---- cross-group reduction in LDS, then one atomic pass per block ----
    #pragma unroll
    for (int r = 0; r < 16; ++r)
        wg[t * 16 + (r ^ (t & 15))] = make_float2(accx[r], accy[r]);
    __syncthreads();
    float* crb = cross + (size_t)b * L_ * 2;
    #pragma unroll
    for (int rr = 0; rr < 4; ++rr) {
        int p  = tid + (rr << 10);
        int tl = p & 255, rv = p >> 8;
        float sx = 0.f, sy = 0.f;
        #pragma unroll
        for (int gg = 0; gg < 4; ++gg) {
            float2 vv = w4[gg * WSZ + tl * 16 + (rv ^ (tl & 15))];
            sx += vv.x; sy += vv.y;
        }
        atomicAdd(&crb[p * 2 + 0], sx);
        atomicAdd(&crb[p * 2 + 1], sy);
    }
}

// ---------------- inverse FFT via conj-forward 3-phase radix-16 ----------------
__global__ __launch_bounds__(256) void k_ifft(const float* __restrict__ cross,
                                              float* __restrict__ mv) {
    __shared__ float2 s[16 * RPAD];
    __shared__ float2 tw256[256];
    const int br4[16] = {0, 8, 4, 12, 2, 10, 6, 14, 1, 9, 5, 13, 3, 11, 7, 15};
    int t = threadIdx.x;
    int b = blockIdx.x;
    {
        int r1 = t >> 4, m2 = t & 15;
        float sn, cs;
        sincospif((float)(r1 * m2) / 128.0f, &sn, &cs);
        tw256[t] = make_float2(cs, -sn);
    }
    const float2* cr = (const float2*)cross + (size_t)b * L_;
    float2 a[16];
    #pragma unroll
    for (int n1 = 0; n1 < 16; ++n1) {
        float2 v = cr[(n1 << 8) + t];
        a[n1] = make_float2(v.x, -v.y);          // conj
    }
    // ---- phase A ----
    fft16(a);
    {
        float sn, cs;
        sincospif((float)t / 2048.0f, &sn, &cs);
        const float2 w1 = make_float2(cs, -sn);
        float2 tw = w1;
        s[t] = a[0];
        #pragma unroll
        for (int k1 = 1; k1 < 16; ++k1) {
            s[k1 * RPAD + t] = cmul(a[br4[k1]], tw);
            tw = cmul(tw, w1);
        }
    }
    __syncthreads();
    // ---- phase B ----
    const int rowB = t >> 4, m2B = t & 15;
    #pragma unroll
    for (int m1 = 0; m1 < 16; ++m1) a[m1] = s[rowB * RPAD + (m1 << 4) + m2B];
    fft16(a);
    #pragma unroll
    for (int r1 = 0; r1 < 16; ++r1)
        s[rowB * RPAD + (r1 << 4) + m2B] = cmul(a[br4[r1]], tw256[(r1 << 4) + m2B]);
    __syncthreads();
    // ---- phase C: write mv directly (k = r2*256 + t, coalesced) ----
    const int k1C = t & 15, r1C = t >> 4;
    #pragma unroll
    for (int m2 = 0; m2 < 16; ++m2) a[m2] = s[k1C * RPAD + (r1C << 4) + m2];
    fft16(a);
    const float scale = 1.0f / ((float)L_ * (float)C_);
    #pragma unroll
    for (int r2 = 0; r2 < 16; ++r2)
        mv[(size_t)b * L_ + (r2 << 8) + t] = a[br4[r2]].x * scale;
}

// ---------------- top-24 + per-batch softmax (register-resident, wave-shuffle) ----------------
__global__ __launch_bounds__(256) void k_topk(const float* __restrict__ mv,
                                              int* __restrict__ idx,
                                              float* __restrict__ wts) {
    __shared__ float wv[4];
    __shared__ int   wi[4];
    __shared__ int   idxL[K_];
    int tid = threadIdx.x;
    float vloc[16];
    #pragma unroll
    for (int r = 0; r < 16; ++r) {
        int tt = tid + (r << 8);
        float ssum = 0.f;
        for (int b = 0; b < B_; ++b) ssum += mv[(size_t)b * L_ + tt];
        vloc[r] = ssum;
    }
    int lane = tid & 63, w = tid >> 6;
    for (int i = 0; i < K_; ++i) {
        float best = -INFINITY; int bi = 1 << 30;
        #pragma unroll
        for (int r = 0; r < 16; ++r) {
            float v = vloc[r]; int ii = tid + (r << 8);
            if (v > best || (v == best && ii < bi)) { best = v; bi = ii; }
        }
        #pragma unroll
        for (int off = 32; off > 0; off >>= 1) {
            float ov = __shfl_down(best, off);
            int   oi = __shfl_down(bi, off);
            if (ov > best || (ov == best && oi < bi)) { best = ov; bi = oi; }
        }
        if (lane == 0) { wv[w] = best; wi[w] = bi; }
        __syncthreads();
        if (tid == 0) {
            float bb = wv[0]; int bj = wi[0];
            for (int j = 1; j < 4; ++j)
                if (wv[j] > bb || (wv[j] == bb && wi[j] < bj)) { bb = wv[j]; bj = wi[j]; }
            idxL[i] = bj; idx[i] = bj;
        }
        __syncthreads();
        int win = idxL[i];
        #pragma unroll
        for (int r = 0; r < 16; ++r)
            if (win == tid + (r << 8)) vloc[r] = -INFINITY;
    }
    if (tid < B_) {
        int b = tid;
        float ww[K_]; float wm = -INFINITY;
        for (int i = 0; i < K_; ++i) { ww[i] = mv[(size_t)b * L_ + idxL[i]]; wm = fmaxf(wm, ww[i]); }
        float ssum = 0.f;
        for (int i = 0; i < K_; ++i) { ww[i] = expf(ww[i] - wm); ssum += ww[i]; }
        float inv = 1.f / ssum;
        for (int i = 0; i < K_; ++i) wts[b * K_ + i] = ww[i] * inv;
    }
}

// ---------------- 24-tap circulant gather-sum, LDS tau-ring version ----------------
__global__ __launch_bounds__(256) void k_agg(const float* __restrict__ vals,
                                             const int* __restrict__ idx,
                                             const float* __restrict__ wts,
                                             float* __restrict__ out) {
    __shared__ float4 sv[L_];      // 64 KB ring: 2 blocks/CU
    __shared__ int   di[K_];
    __shared__ float dw[K_];
    const int tid = threadIdx.x;
    // XCD-aware bijective decode: 2048 blocks; xcd = id&7 owns work [xcd*256, xcd*256+256)
    int id = blockIdx.x;
    int wk = ((id & 7) << 8) | (id >> 3);
    int b  = wk >> 7;              // 0..15 (2 batches per XCD)
    int c0 = (wk & 127) << 2;      // channel-quad start

    if (tid < K_) { di[tid] = idx[tid]; dw[tid] = wts[b * K_ + tid]; }

    // ---- stage: 16 iters x 256 lanes x 16B, LDS dest linear (wave-uniform base + lane*16)
    const float* gbase = vals + (size_t)b * L_ * C_ + c0;
    #pragma unroll
    for (int it = 0; it < 16; ++it) {
        int tau = (it << 8) + tid;
        const float* g = gbase + (size_t)tau * C_;
        float4* l = &sv[(it << 8) + ((tid >> 6) << 6)];   // wave-uniform within each wave
        __builtin_amdgcn_global_load_lds(
            (const __attribute__((address_space(1))) uint32_t*)g,
            (__attribute__((address_space(3))) uint32_t*)l,
            16, 0, 0);
    }
    __syncthreads();   // drains vmcnt before barrier

    // taps/weights to registers (fully-unrolled static indexing)
    int   dir[K_]; float dwr[K_];
    #pragma unroll
    for (int i = 0; i < K_; ++i) { dir[i] = di[i]; dwr[i] = dw[i]; }

    float* obase = out + (size_t)b * L_ * C_ + c0;
    for (int r = 0; r < 16; ++r) {
        int tau = (r << 8) + tid;
        float4 acc = make_float4(0.f, 0.f, 0.f, 0.f);
        #pragma unroll
        for (int i = 0; i < K_; ++i) {
            float4 x = sv[(tau + dir[i]) & (L_ - 1)];
            float w = dwr[i];
            acc.x = fmaf(w, x.x, acc.x);
            acc.y = fmaf(w, x.y, acc.y);
            acc.z = fmaf(w, x.z, acc.z);
            acc.w = fmaf(w, x.w, acc.w);
        }
        *(float4*)(obase + (size_t)tau * C_) = acc;
    }
}

extern "C" void kernel_launch(void* const* d_in, const int* in_sizes, int n_in,
                              void* d_out, int out_size, void* d_ws, size_t ws_size,
                              hipStream_t stream) {
    const float* q = (const float*)d_in[0];
    const float* k = (const float*)d_in[1];
    const float* v = (const float*)d_in[2];
    float* out = (float*)d_out;
    char* ws = (char*)d_ws;

    // ws layout: [cross 512KB | mv 256KB | idx | wts]  (no z: fully fused FFT)
    float* cross = (float*)ws;
    float* mv    = (float*)(ws + (1 << 20));
    int*   idx   = (int*)(ws + (1 << 20) + (1 << 18));
    float* wts   = (float*)(ws + (1 << 20) + (1 << 18) + 4096);

    k_zero<<<(B_ * L_ * 2 + 255) / 256, 256, 0, stream>>>(cross, B_ * L_ * 2);
    k_fft_full<<<B_ * (C_ / 4), 1024, 0, stream>>>(q, k, cross);
    k_ifft<<<B_, 256, 0, stream>>>(cross, mv);
    k_topk<<<1, 256, 0, stream>>>(mv, idx, wts);
    k_agg<<<B_ * (C_ / 4), 256, 0, stream>>>(v, idx, wts, out);
}